// Round 6
// baseline (1752.657 us; speedup 1.0000x reference)
//
#include <hip/hip_runtime.h>
#include <math.h>

constexpr int B = 8, C = 64, H = 256, W = 256, HWc = H * W, N = 10;

typedef short bf8 __attribute__((ext_vector_type(8)));    // 8 x bf16 (4 VGPR)
typedef float f4  __attribute__((ext_vector_type(4)));    // MFMA accum
typedef unsigned short ushort;

__device__ __forceinline__ ushort f2bf(float f) {
  unsigned u = __builtin_bit_cast(unsigned, f);
  unsigned r = (u + 0x7fffu + ((u >> 16) & 1u)) >> 16;
  return (ushort)r;
}
__device__ __forceinline__ float bf2f(ushort h) {
  unsigned u = ((unsigned)h) << 16;
  return __builtin_bit_cast(float, u);
}

// ---------------- LayerNorm: NCHW fp32 -> NHWC bf16 ----------------
__global__ __launch_bounds__(256) void ln_k(
    const float* __restrict__ x, const float* __restrict__ g,
    const float* __restrict__ bt, ushort* __restrict__ xn) {
  int pix = blockIdx.x * 256 + threadIdx.x;
  int b = blockIdx.y;
  const float* xp = x + (size_t)b * C * HWc + pix;
  float v[64];
  float s = 0.f, s2 = 0.f;
#pragma unroll
  for (int c = 0; c < 64; c++) {
    v[c] = xp[(size_t)c * HWc];
    s += v[c]; s2 += v[c] * v[c];
  }
  float mu = s * (1.f / 64);
  float var = s2 * (1.f / 64) - mu * mu;
  float rstd = rsqrtf(var + 1e-5f);
  ushort* op = xn + ((size_t)b * HWc + pix) * 64;
#pragma unroll
  for (int ch = 0; ch < 8; ch++) {
    union { ushort us[8]; int4 v4; } pk;
#pragma unroll
    for (int j = 0; j < 8; j++) {
      int c = ch * 8 + j;
      pk.us[j] = f2bf((v[c] - mu) * rstd * g[c] + bt[c]);
    }
    *reinterpret_cast<int4*>(op + ch * 8) = pk.v4;
  }
}

// ---------------- weight prep: OIHW fp32 -> MFMA fragment layout bf16 ----------------
// frags[conv][((s*4+cf)*64+lane)*8+j] = w[co][ci][tap]
//   co = cf*16 + (lane&15); tap = s>>1; ci = (s&1)*32 + (lane>>4)*8 + j
__global__ void prep_w(const float* __restrict__ w3, const float* __restrict__ wu,
                       const float* __restrict__ wd, ushort* __restrict__ frags) {
  int idx = blockIdx.x * 256 + threadIdx.x;
  if (idx >= 3 * 4608) return;
  int conv = idx / 4608, r = idx % 4608;
  int s = r >> 8, cf = (r >> 6) & 3, lane = r & 63;
  const float* w = (conv == 0) ? w3 : (conv == 1) ? wu : wd;
  int co = (cf << 4) + (lane & 15);
  int tap = s >> 1;
  ushort* o = frags + conv * 36864 + ((size_t)r) * 8;
#pragma unroll
  for (int j = 0; j < 8; j++) {
    int ci = ((s & 1) << 5) + ((lane >> 4) << 3) + j;
    o[j] = f2bf(w[(co * 64 + ci) * 9 + tap]);
  }
}

// ======== shared device helpers for the conv main loop (ci-half staged) ========
// LDS stage layout (per ci-half): pixel pix (18x18), chunk ch(0..3 of 8 ci):
//   off = pix*64 + ch*16 ^ (((pix%18 >>1)&3)<<4)
__device__ __forceinline__ void stage_half(
    char* lds, const ushort* __restrict__ in, int b, int h0, int w0,
    int ch2, int tid) {
  for (int idx = tid; idx < 18 * 18 * 4; idx += 256) {
    int pix = idx >> 2, ch = idx & 3;
    int r = pix / 18, c = pix % 18;
    int gh = h0 + r - 1, gw = w0 + c - 1;
    int4 v = make_int4(0, 0, 0, 0);
    if (gh >= 0 && gh < H && gw >= 0 && gw < W)
      v = *reinterpret_cast<const int4*>(
          in + (((size_t)b * H + gh) * W + gw) * 64 + ch2 * 32 + ch * 8);
    int off = ((pix << 6) + (ch << 4)) ^ (((c >> 1) & 3) << 4);
    *reinterpret_cast<int4*>(lds + off) = v;
  }
}

// compute one ci-half (3 dx groups); acc[f] += conv contributions
__device__ __forceinline__ void compute_half(
    const char* lds, const bf8* __restrict__ wf, int ch2,
    int wave, int lm, int lk, f4 (&acc)[16]) {
#pragma unroll
  for (int dx = 0; dx < 3; dx++) {
    bf8 wb3[3];
#pragma unroll
    for (int dy = 0; dy < 3; dy++) {
      int s = ((dy * 3 + dx) << 1) | ch2;
      wb3[dy] = wf[(s * 4 + wave) * 64 + (lk << 4) + lm];
    }
    int lc = lm + dx;
    int swz = ((lc >> 1) & 3) << 4;
    bf8 a[18];
#pragma unroll
    for (int r = 0; r < 18; r++) {
      int off = (((r * 18 + lc) << 6) + (lk << 4)) ^ swz;
      a[r] = *reinterpret_cast<const bf8*>(lds + off);
    }
#pragma unroll
    for (int dy = 0; dy < 3; dy++)
#pragma unroll
      for (int f = 0; f < 16; f++)
        acc[f] = __builtin_amdgcn_mfma_f32_16x16x32_bf16(a[f + dy], wb3[dy], acc[f], 0, 0, 0);
  }
}

// ---------------- MFMA implicit-GEMM 3x3 conv ----------------
// in: NHWC bf16. OM=0: out NHWC bf16 (+GELU if ACT). OM=1: out NCHW fp32 + residual.
template <int ACT, int OM>
__global__ __launch_bounds__(256, 5) void conv_mfma(
    const ushort* __restrict__ in, const ushort* __restrict__ wfrag,
    const float* __restrict__ bias, const float* __restrict__ resid,
    ushort* __restrict__ outb, float* __restrict__ outf) {
  __shared__ char lds[20736];  // stage half (20736) / epilogue quarter (16384)
  int tid = threadIdx.x;
  int b = blockIdx.z;
  int h0 = blockIdx.y * 16, w0 = blockIdx.x * 16;
  int wave = tid >> 6, lane = tid & 63;
  int lm = lane & 15, lk = lane >> 4;
  const bf8* wf = reinterpret_cast<const bf8*>(wfrag);

  f4 acc[16];
  {
    float bv = bias[(wave << 4) + lm];
    f4 ini = {bv, bv, bv, bv};
#pragma unroll
    for (int f = 0; f < 16; f++) acc[f] = ini;
  }

#pragma unroll
  for (int ch2 = 0; ch2 < 2; ch2++) {
    if (ch2) __syncthreads();   // all reads of previous half done
    stage_half(lds, in, b, h0, w0, ch2, tid);
    __syncthreads();
    compute_half(lds, wf, ch2, wave, lm, lk, acc);
  }
  __syncthreads();

  float* ldsf = reinterpret_cast<float*>(lds);
  if (OM == 0) {
    // 4 quarters of 4 pixel-rows: 4*16 px * 64 co * 4B = 16 KB
    for (int q = 0; q < 4; q++) {
      if (q) __syncthreads();
#pragma unroll
      for (int fr = 0; fr < 4; fr++) {
        int f = q * 4 + fr;
        int co = (wave << 4) + lm;
#pragma unroll
        for (int r = 0; r < 4; r++) {
          int p = (lk << 2) + r;
          ldsf[fr * 1024 + p * 64 + (co ^ ((p & 12) << 2))] = acc[f][r];
        }
      }
      __syncthreads();
#pragma unroll
      for (int i = 0; i < 2; i++) {
        int q2 = i * 256 + tid;               // 0..511
        int co8 = q2 & 7, p = (q2 >> 3) & 15, fr = q2 >> 7;
        int cb = (co8 * 8) ^ ((p & 12) << 2);
        f4 v0 = *reinterpret_cast<f4*>(&ldsf[fr * 1024 + p * 64 + cb]);
        f4 v1 = *reinterpret_cast<f4*>(&ldsf[fr * 1024 + p * 64 + cb + 4]);
        float vv[8] = {v0[0], v0[1], v0[2], v0[3], v1[0], v1[1], v1[2], v1[3]};
        union { ushort us[8]; int4 i4; } pk;
#pragma unroll
        for (int j = 0; j < 8; j++) {
          float v = vv[j];
          if (ACT) v = 0.5f * v * (1.f + erff(v * 0.70710678118654752f));
          pk.us[j] = f2bf(v);
        }
        *reinterpret_cast<int4*>(
            outb + (((size_t)b * H + h0 + q * 4 + fr) * W + w0 + p) * 64 + co8 * 8) = pk.i4;
      }
    }
  } else {
    // NCHW fp32 + residual; 4 quarters of 16 co (wave q's group): 16*256*4B = 16 KB
    for (int q = 0; q < 4; q++) {
      if (q) __syncthreads();
      if (wave == q) {
#pragma unroll
        for (int f = 0; f < 16; f++) {
          int pxl = (f << 4) + (lk << 2);
          int pxs = pxl ^ ((lm & 7) << 2);
          *reinterpret_cast<f4*>(&ldsf[lm * 256 + pxs]) = acc[f];
        }
      }
      __syncthreads();
#pragma unroll
      for (int i = 0; i < 4; i++) {
        int q2 = i * 256 + tid;               // 0..1023
        int chunk = q2 & 63, co16 = q2 >> 6;
        int pq = chunk * 4;                    // unswizzled pixel base
        int pxs = pq ^ ((co16 & 7) << 2);
        f4 v = *reinterpret_cast<f4*>(&ldsf[co16 * 256 + pxs]);
        int co = q * 16 + co16;
        size_t o = ((size_t)(b * 64 + co)) * HWc +
                   (size_t)(h0 + (pq >> 4)) * W + w0 + (pq & 15);
        float4 rv = *reinterpret_cast<const float4*>(resid + o);
        float4 ov;
        ov.x = v[0] + rv.x; ov.y = v[1] + rv.y; ov.z = v[2] + rv.z; ov.w = v[3] + rv.w;
        *reinterpret_cast<float4*>(outf + o) = ov;
      }
    }
  }
}

// ---------------- fused up-conv + channel mix ----------------
// in: x1 NHWC bf16 -> xm (kept in LDS as bf16 tile) -> xm2 = Wm^T-mix -> NHWC bf16 out
__global__ __launch_bounds__(256, 3) void upmix_mfma(
    const ushort* __restrict__ in, const ushort* __restrict__ wfrag,
    const float* __restrict__ bias, const ushort* __restrict__ wmf,
    ushort* __restrict__ out) {
  __shared__ char ldsS[20736];   // stage half / final epilogue quarter
  __shared__ char ldsX[32768];   // xm tile [pix 0..255][k 0..63] bf16, mix-swizzled
  int tid = threadIdx.x;
  int b = blockIdx.z;
  int h0 = blockIdx.y * 16, w0 = blockIdx.x * 16;
  int wave = tid >> 6, lane = tid & 63;
  int lm = lane & 15, lk = lane >> 4;
  const bf8* wf = reinterpret_cast<const bf8*>(wfrag);

  // preload mix B-frags (Wm for this batch)
  const bf8* wmb = reinterpret_cast<const bf8*>(wmf + (size_t)b * 4096);
  bf8 wm[2];
#pragma unroll
  for (int s = 0; s < 2; s++) wm[s] = wmb[(s * 4 + wave) * 64 + lane];

  f4 acc[16];
  {
    float bv = bias[(wave << 4) + lm];
    f4 ini = {bv, bv, bv, bv};
#pragma unroll
    for (int f = 0; f < 16; f++) acc[f] = ini;
  }

  // phase 1: up-conv
#pragma unroll
  for (int ch2 = 0; ch2 < 2; ch2++) {
    if (ch2) __syncthreads();
    stage_half(ldsS, in, b, h0, w0, ch2, tid);
    __syncthreads();
    compute_half(ldsS, wf, ch2, wave, lm, lk, acc);
  }

  // scatter acc -> xm tile (bf16) in mix staging layout:
  // value = xm[row f][pxcol lk*4+r][k wave*16+lm]
  // off = pix*128 + k*2 ^ ((pix&15 &7)<<4)
#pragma unroll
  for (int f = 0; f < 16; f++) {
#pragma unroll
    for (int r = 0; r < 4; r++) {
      int pc = (lk << 2) + r;                 // pixel col 0..15
      int pix = (f << 4) + pc;
      int off = ((pix << 7) + ((wave << 4) + lm) * 2) ^ ((pc & 7) << 4);
      *reinterpret_cast<ushort*>(ldsX + off) = f2bf(acc[f][r]);
    }
  }
  __syncthreads();

  // phase 2: mix MFMA (A from ldsX, B = wm)
  f4 acc2[16];
#pragma unroll
  for (int f = 0; f < 16; f++) acc2[f] = (f4){0.f, 0.f, 0.f, 0.f};
#pragma unroll
  for (int s = 0; s < 2; s++) {
    int kbyte = ((s << 5) + (lk << 3)) << 1;
#pragma unroll
    for (int f = 0; f < 16; f++) {
      int off = ((((f << 4) + lm) << 7) + kbyte) ^ ((lm & 7) << 4);
      bf8 a = *reinterpret_cast<const bf8*>(ldsX + off);
      acc2[f] = __builtin_amdgcn_mfma_f32_16x16x32_bf16(a, wm[s], acc2[f], 0, 0, 0);
    }
  }
  __syncthreads();

  // epilogue: quartered transpose via ldsS -> NHWC bf16 global
  float* ldsf = reinterpret_cast<float*>(ldsS);
  for (int q = 0; q < 4; q++) {
    if (q) __syncthreads();
#pragma unroll
    for (int fr = 0; fr < 4; fr++) {
      int f = q * 4 + fr;
      int co = (wave << 4) + lm;
#pragma unroll
      for (int r = 0; r < 4; r++) {
        int p = (lk << 2) + r;
        ldsf[fr * 1024 + p * 64 + (co ^ ((p & 12) << 2))] = acc2[f][r];
      }
    }
    __syncthreads();
#pragma unroll
    for (int i = 0; i < 2; i++) {
      int q2 = i * 256 + tid;
      int co8 = q2 & 7, p = (q2 >> 3) & 15, fr = q2 >> 7;
      int cb = (co8 * 8) ^ ((p & 12) << 2);
      f4 v0 = *reinterpret_cast<f4*>(&ldsf[fr * 1024 + p * 64 + cb]);
      f4 v1 = *reinterpret_cast<f4*>(&ldsf[fr * 1024 + p * 64 + cb + 4]);
      float vv[8] = {v0[0], v0[1], v0[2], v0[3], v1[0], v1[1], v1[2], v1[3]};
      union { ushort us[8]; int4 i4; } pk;
#pragma unroll
      for (int j = 0; j < 8; j++) pk.us[j] = f2bf(vv[j]);
      *reinterpret_cast<int4*>(
          out + (((size_t)b * H + h0 + q * 4 + fr) * W + w0 + p) * 64 + co8 * 8) = pk.i4;
    }
  }
}

// ---------------- depthwise 3x3 + GAP (NHWC bf16 in) ----------------
__global__ __launch_bounds__(256) void dwgap_k(
    const ushort* __restrict__ x1, const float* __restrict__ dww,
    float* __restrict__ pooled) {
  int c = threadIdx.x & 63;
  int q = threadIdx.x >> 6;
  int seg = blockIdx.x * 4 + q;  // 0..1023
  int row = seg >> 2;
  int wbase = (seg & 3) * 64;
  int b = blockIdx.y;
  float wv[9];
#pragma unroll
  for (int t = 0; t < 9; t++) wv[t] = dww[c * 9 + t];

  auto ld = [&](int hh, int ww) -> float {
    if (hh < 0 || hh >= H || ww < 0 || ww >= W) return 0.f;
    return bf2f(x1[(((size_t)b * H + hh) * W + ww) * 64 + c]);
  };
  float v[3][3];
#pragma unroll
  for (int dy = 0; dy < 3; dy++) {
    v[dy][0] = ld(row + dy - 1, wbase - 1);
    v[dy][1] = ld(row + dy - 1, wbase);
  }
  float acc = 0.f;
  for (int i = 0; i < 64; i++) {
    int w = wbase + i;
#pragma unroll
    for (int dy = 0; dy < 3; dy++) v[dy][2] = ld(row + dy - 1, w + 1);
    float s = 0.f;
#pragma unroll
    for (int dy = 0; dy < 3; dy++)
#pragma unroll
      for (int dx = 0; dx < 3; dx++) s += v[dy][dx] * wv[dy * 3 + dx];
    acc += s;
#pragma unroll
    for (int dy = 0; dy < 3; dy++) { v[dy][0] = v[dy][1]; v[dy][1] = v[dy][2]; }
  }
  atomicAdd(&pooled[b * 64 + c], acc);
}

// ---------------- MLP + softmax + blend -> Wm in B-fragment layout ----------------
__global__ void mlp_k(const float* __restrict__ pooled, const float* __restrict__ dwb,
                      const float* __restrict__ c1w, const float* __restrict__ c1b,
                      const float* __restrict__ c2w, const float* __restrict__ c2b,
                      const float* __restrict__ basep, ushort* __restrict__ wmf) {
  int b = blockIdx.x;
  int t = threadIdx.x;  // 64 threads
  __shared__ float pm[64], p1[64], p2[16];
  pm[t] = pooled[b * 64 + t] * (1.f / HWc) + dwb[t];
  __syncthreads();
  float a = c1b[t];
  for (int ci = 0; ci < 64; ci++) a += pm[ci] * c1w[t * 64 + ci];
  p1[t] = fmaxf(a, 0.f);
  __syncthreads();
  if (t < N) {
    float a2 = c2b[t];
    for (int ci = 0; ci < 64; ci++) a2 += p1[ci] * c2w[t * 64 + ci];
    p2[t] = a2;
  }
  __syncthreads();
  float m = -1e30f;
  for (int n = 0; n < N; n++) m = fmaxf(m, p2[n]);
  float e[N], s = 0.f;
  for (int n = 0; n < N; n++) { e[n] = expf(p2[n] - m); s += e[n]; }
  float inv = 1.f / s;
  // wmf[b][(s2*4+cf)*64+lane][j] = Wm[k][l], k = s2*32+(lane>>4)*8+j, l = cf*16+(lane&15)
  for (int idx = t; idx < 4096; idx += 64) {
    int j = idx & 7, lane = (idx >> 3) & 63, cf = (idx >> 9) & 3, s2 = idx >> 11;
    int k = (s2 << 5) + ((lane >> 4) << 3) + j;
    int l = (cf << 4) + (lane & 15);
    float acc = 0.f;
    for (int n = 0; n < N; n++) acc += e[n] * inv * basep[n * 4096 + k * 64 + l];
    wmf[(size_t)b * 4096 + idx] = f2bf(acc);
  }
}

__global__ void zero_k(float* p, int n) {
  int i = blockIdx.x * 256 + threadIdx.x;
  if (i < n) p[i] = 0.f;
}

extern "C" void kernel_launch(void* const* d_in, const int* in_sizes, int n_in,
                              void* d_out, int out_size, void* d_ws, size_t ws_size,
                              hipStream_t stream) {
  const float* x       = (const float*)d_in[0];
  const float* ln_g    = (const float*)d_in[1];
  const float* ln_b    = (const float*)d_in[2];
  const float* conv3_w = (const float*)d_in[3];
  const float* conv3_b = (const float*)d_in[4];
  const float* dw_w    = (const float*)d_in[5];
  const float* dw_b    = (const float*)d_in[6];
  const float* c1_w    = (const float*)d_in[7];
  const float* c1_b    = (const float*)d_in[8];
  const float* c2_w    = (const float*)d_in[9];
  const float* c2_b    = (const float*)d_in[10];
  const float* basep   = (const float*)d_in[11];
  const float* up_w    = (const float*)d_in[12];
  const float* up_b    = (const float*)d_in[13];
  const float* down_w  = (const float*)d_in[14];
  const float* down_b  = (const float*)d_in[15];
  float* out = (float*)d_out;

  char* wsb = (char*)d_ws;
  size_t big = (size_t)B * HWc * 64 * sizeof(ushort);  // 67,108,864
  ushort* bufA   = (ushort*)wsb;
  ushort* bufB   = (ushort*)(wsb + big);
  ushort* wfrags = (ushort*)(wsb + 2 * big);
  ushort* wmfrag = (ushort*)(wsb + 2 * big + 3 * 36864 * 2);
  float*  pooled = (float*)(wsb + 2 * big + 3 * 36864 * 2 + 8 * 4096 * 2);

  prep_w<<<54, 256, 0, stream>>>(conv3_w, up_w, down_w, wfrags);
  zero_k<<<2, 256, 0, stream>>>(pooled, B * C);
  // 1. LN: x -> bufA (NHWC bf16)
  ln_k<<<dim3(HWc / 256, B), 256, 0, stream>>>(x, ln_g, ln_b, bufA);
  // 2. conv3 + GELU: bufA -> bufB (x1)
  conv_mfma<1, 0><<<dim3(16, 16, B), 256, 0, stream>>>(
      bufA, wfrags + 0 * 36864, conv3_b, nullptr, bufB, nullptr);
  // 3. dw + GAP: bufB -> pooled
  dwgap_k<<<dim3(256, B), 256, 0, stream>>>(bufB, dw_w, pooled);
  // 4. MLP + blend: pooled -> wmfrag
  mlp_k<<<B, 64, 0, stream>>>(pooled, dw_b, c1_w, c1_b, c2_w, c2_b, basep, wmfrag);
  // 5+6. fused up conv + mix: bufB -> bufA (xm2, NHWC bf16)
  upmix_mfma<<<dim3(16, 16, B), 256, 0, stream>>>(
      bufB, wfrags + 1 * 36864, up_b, wmfrag, bufA);
  // 7. down conv + residual: bufA -> out (NCHW fp32)
  conv_mfma<0, 1><<<dim3(16, 16, B), 256, 0, stream>>>(
      bufA, wfrags + 2 * 36864, down_b, x, nullptr, out);
}

// Round 7
// 404.219 us; speedup vs baseline: 4.3359x; 4.3359x over previous
//
#include <hip/hip_runtime.h>
#include <math.h>

constexpr int B = 8, C = 64, H = 256, W = 256, HWc = H * W, N = 10;

typedef short bf8 __attribute__((ext_vector_type(8)));    // 8 x bf16 (4 VGPR)
typedef float f4  __attribute__((ext_vector_type(4)));    // MFMA accum
typedef unsigned short ushort;

__device__ __forceinline__ ushort f2bf(float f) {
  unsigned u = __builtin_bit_cast(unsigned, f);
  unsigned r = (u + 0x7fffu + ((u >> 16) & 1u)) >> 16;
  return (ushort)r;
}
__device__ __forceinline__ float bf2f(ushort h) {
  unsigned u = ((unsigned)h) << 16;
  return __builtin_bit_cast(float, u);
}

// ---------------- LayerNorm: NCHW fp32 -> NHWC bf16 ----------------
__global__ __launch_bounds__(256) void ln_k(
    const float* __restrict__ x, const float* __restrict__ g,
    const float* __restrict__ bt, ushort* __restrict__ xn) {
  int pix = blockIdx.x * 256 + threadIdx.x;
  int b = blockIdx.y;
  const float* xp = x + (size_t)b * C * HWc + pix;
  float v[64];
  float s = 0.f, s2 = 0.f;
#pragma unroll
  for (int c = 0; c < 64; c++) {
    v[c] = xp[(size_t)c * HWc];
    s += v[c]; s2 += v[c] * v[c];
  }
  float mu = s * (1.f / 64);
  float var = s2 * (1.f / 64) - mu * mu;
  float rstd = rsqrtf(var + 1e-5f);
  ushort* op = xn + ((size_t)b * HWc + pix) * 64;
#pragma unroll
  for (int ch = 0; ch < 8; ch++) {
    union { ushort us[8]; int4 v4; } pk;
#pragma unroll
    for (int j = 0; j < 8; j++) {
      int c = ch * 8 + j;
      pk.us[j] = f2bf((v[c] - mu) * rstd * g[c] + bt[c]);
    }
    *reinterpret_cast<int4*>(op + ch * 8) = pk.v4;
  }
}

// ---------------- weight prep: OIHW fp32 -> MFMA fragment layout bf16 ----------------
// frags[conv][((s*4+cf)*64+lane)*8+j] = w[co][ci][tap]
//   co = cf*16 + (lane&15); tap = s>>1; ci = (s&1)*32 + (lane>>4)*8 + j
__global__ void prep_w(const float* __restrict__ w3, const float* __restrict__ wu,
                       const float* __restrict__ wd, ushort* __restrict__ frags) {
  int idx = blockIdx.x * 256 + threadIdx.x;
  if (idx >= 3 * 4608) return;
  int conv = idx / 4608, r = idx % 4608;
  int s = r >> 8, cf = (r >> 6) & 3, lane = r & 63;
  const float* w = (conv == 0) ? w3 : (conv == 1) ? wu : wd;
  int co = (cf << 4) + (lane & 15);
  int tap = s >> 1;
  ushort* o = frags + conv * 36864 + ((size_t)r) * 8;
#pragma unroll
  for (int j = 0; j < 8; j++) {
    int ci = ((s & 1) << 5) + ((lane >> 4) << 3) + j;
    o[j] = f2bf(w[(co * 64 + ci) * 9 + tap]);
  }
}

// ======== shared device helpers for the conv main loop (ci-half staged) ========
// LDS stage layout (per ci-half): pixel pix (18x18), chunk ch(0..3 of 8 ci):
//   off = pix*64 + ch*16 ^ (((pix%18 >>1)&3)<<4)
__device__ __forceinline__ void stage_half(
    char* lds, const ushort* __restrict__ in, int b, int h0, int w0,
    int ch2, int tid) {
  for (int idx = tid; idx < 18 * 18 * 4; idx += 256) {
    int pix = idx >> 2, ch = idx & 3;
    int r = pix / 18, c = pix % 18;
    int gh = h0 + r - 1, gw = w0 + c - 1;
    int4 v = make_int4(0, 0, 0, 0);
    if (gh >= 0 && gh < H && gw >= 0 && gw < W)
      v = *reinterpret_cast<const int4*>(
          in + (((size_t)b * H + gh) * W + gw) * 64 + ch2 * 32 + ch * 8);
    int off = ((pix << 6) + (ch << 4)) ^ (((c >> 1) & 3) << 4);
    *reinterpret_cast<int4*>(lds + off) = v;
  }
}

// compute one ci-half (3 dx groups); acc[f] += conv contributions
__device__ __forceinline__ void compute_half(
    const char* lds, const bf8* __restrict__ wf, int ch2,
    int wave, int lm, int lk, f4 (&acc)[16]) {
#pragma unroll
  for (int dx = 0; dx < 3; dx++) {
    bf8 wb3[3];
#pragma unroll
    for (int dy = 0; dy < 3; dy++) {
      int s = ((dy * 3 + dx) << 1) | ch2;
      wb3[dy] = wf[(s * 4 + wave) * 64 + (lk << 4) + lm];
    }
    int lc = lm + dx;
    int swz = ((lc >> 1) & 3) << 4;
    bf8 a[18];
#pragma unroll
    for (int r = 0; r < 18; r++) {
      int off = (((r * 18 + lc) << 6) + (lk << 4)) ^ swz;
      a[r] = *reinterpret_cast<const bf8*>(lds + off);
    }
#pragma unroll
    for (int dy = 0; dy < 3; dy++)
#pragma unroll
      for (int f = 0; f < 16; f++)
        acc[f] = __builtin_amdgcn_mfma_f32_16x16x32_bf16(a[f + dy], wb3[dy], acc[f], 0, 0, 0);
  }
}

// ---------------- MFMA implicit-GEMM 3x3 conv ----------------
// in: NHWC bf16. OM=0: out NHWC bf16 (+GELU if ACT). OM=1: out NCHW fp32 + residual.
// launch_bounds (256,2): proven no-spill point (R5: VGPR=100). Occupancy comes
// from the 20.7 KB LDS footprint (up to 7 blocks/CU), NOT from coercing the
// register allocator — (256,5) capped VGPR to 48 and spilled acc (R6, 2.8 GB/dispatch).
template <int ACT, int OM>
__global__ __launch_bounds__(256, 2) void conv_mfma(
    const ushort* __restrict__ in, const ushort* __restrict__ wfrag,
    const float* __restrict__ bias, const float* __restrict__ resid,
    ushort* __restrict__ outb, float* __restrict__ outf) {
  __shared__ char lds[20736];  // stage half (20736) / epilogue quarter (16384)
  int tid = threadIdx.x;
  int b = blockIdx.z;
  int h0 = blockIdx.y * 16, w0 = blockIdx.x * 16;
  int wave = tid >> 6, lane = tid & 63;
  int lm = lane & 15, lk = lane >> 4;
  const bf8* wf = reinterpret_cast<const bf8*>(wfrag);

  f4 acc[16];
  {
    float bv = bias[(wave << 4) + lm];
    f4 ini = {bv, bv, bv, bv};
#pragma unroll
    for (int f = 0; f < 16; f++) acc[f] = ini;
  }

#pragma unroll
  for (int ch2 = 0; ch2 < 2; ch2++) {
    if (ch2) __syncthreads();   // all reads of previous half done
    stage_half(lds, in, b, h0, w0, ch2, tid);
    __syncthreads();
    compute_half(lds, wf, ch2, wave, lm, lk, acc);
  }
  __syncthreads();

  float* ldsf = reinterpret_cast<float*>(lds);
  if (OM == 0) {
    // 4 quarters of 4 pixel-rows: 4*16 px * 64 co * 4B = 16 KB
    for (int q = 0; q < 4; q++) {
      if (q) __syncthreads();
#pragma unroll
      for (int fr = 0; fr < 4; fr++) {
        int f = q * 4 + fr;
        int co = (wave << 4) + lm;
#pragma unroll
        for (int r = 0; r < 4; r++) {
          int p = (lk << 2) + r;
          ldsf[fr * 1024 + p * 64 + (co ^ ((p & 12) << 2))] = acc[f][r];
        }
      }
      __syncthreads();
#pragma unroll
      for (int i = 0; i < 2; i++) {
        int q2 = i * 256 + tid;               // 0..511
        int co8 = q2 & 7, p = (q2 >> 3) & 15, fr = q2 >> 7;
        int cb = (co8 * 8) ^ ((p & 12) << 2);
        f4 v0 = *reinterpret_cast<f4*>(&ldsf[fr * 1024 + p * 64 + cb]);
        f4 v1 = *reinterpret_cast<f4*>(&ldsf[fr * 1024 + p * 64 + cb + 4]);
        float vv[8] = {v0[0], v0[1], v0[2], v0[3], v1[0], v1[1], v1[2], v1[3]};
        union { ushort us[8]; int4 i4; } pk;
#pragma unroll
        for (int j = 0; j < 8; j++) {
          float v = vv[j];
          if (ACT) v = 0.5f * v * (1.f + erff(v * 0.70710678118654752f));
          pk.us[j] = f2bf(v);
        }
        *reinterpret_cast<int4*>(
            outb + (((size_t)b * H + h0 + q * 4 + fr) * W + w0 + p) * 64 + co8 * 8) = pk.i4;
      }
    }
  } else {
    // NCHW fp32 + residual; 4 quarters of 16 co (wave q's group): 16*256*4B = 16 KB
    for (int q = 0; q < 4; q++) {
      if (q) __syncthreads();
      if (wave == q) {
#pragma unroll
        for (int f = 0; f < 16; f++) {
          int pxl = (f << 4) + (lk << 2);
          int pxs = pxl ^ ((lm & 7) << 2);
          *reinterpret_cast<f4*>(&ldsf[lm * 256 + pxs]) = acc[f];
        }
      }
      __syncthreads();
#pragma unroll
      for (int i = 0; i < 4; i++) {
        int q2 = i * 256 + tid;               // 0..1023
        int chunk = q2 & 63, co16 = q2 >> 6;
        int pq = chunk * 4;                    // unswizzled pixel base
        int pxs = pq ^ ((co16 & 7) << 2);
        f4 v = *reinterpret_cast<f4*>(&ldsf[co16 * 256 + pxs]);
        int co = q * 16 + co16;
        size_t o = ((size_t)(b * 64 + co)) * HWc +
                   (size_t)(h0 + (pq >> 4)) * W + w0 + (pq & 15);
        float4 rv = *reinterpret_cast<const float4*>(resid + o);
        float4 ov;
        ov.x = v[0] + rv.x; ov.y = v[1] + rv.y; ov.z = v[2] + rv.z; ov.w = v[3] + rv.w;
        *reinterpret_cast<float4*>(outf + o) = ov;
      }
    }
  }
}

// ---------------- fused up-conv + channel mix ----------------
// in: x1 NHWC bf16 -> xm (kept in LDS as bf16 tile) -> xm2 = Wm^T-mix -> NHWC bf16 out
__global__ __launch_bounds__(256, 2) void upmix_mfma(
    const ushort* __restrict__ in, const ushort* __restrict__ wfrag,
    const float* __restrict__ bias, const ushort* __restrict__ wmf,
    ushort* __restrict__ out) {
  __shared__ char ldsS[20736];   // stage half / final epilogue quarter
  __shared__ char ldsX[32768];   // xm tile [pix 0..255][k 0..63] bf16, mix-swizzled
  int tid = threadIdx.x;
  int b = blockIdx.z;
  int h0 = blockIdx.y * 16, w0 = blockIdx.x * 16;
  int wave = tid >> 6, lane = tid & 63;
  int lm = lane & 15, lk = lane >> 4;
  const bf8* wf = reinterpret_cast<const bf8*>(wfrag);

  // preload mix B-frags (Wm for this batch)
  const bf8* wmb = reinterpret_cast<const bf8*>(wmf + (size_t)b * 4096);
  bf8 wm[2];
#pragma unroll
  for (int s = 0; s < 2; s++) wm[s] = wmb[(s * 4 + wave) * 64 + lane];

  f4 acc[16];
  {
    float bv = bias[(wave << 4) + lm];
    f4 ini = {bv, bv, bv, bv};
#pragma unroll
    for (int f = 0; f < 16; f++) acc[f] = ini;
  }

  // phase 1: up-conv
#pragma unroll
  for (int ch2 = 0; ch2 < 2; ch2++) {
    if (ch2) __syncthreads();
    stage_half(ldsS, in, b, h0, w0, ch2, tid);
    __syncthreads();
    compute_half(ldsS, wf, ch2, wave, lm, lk, acc);
  }

  // scatter acc -> xm tile (bf16) in mix staging layout:
  // value = xm[row f][pxcol lk*4+r][k wave*16+lm]
  // off = pix*128 + k*2 ^ ((pix&15 &7)<<4)
#pragma unroll
  for (int f = 0; f < 16; f++) {
#pragma unroll
    for (int r = 0; r < 4; r++) {
      int pc = (lk << 2) + r;                 // pixel col 0..15
      int pix = (f << 4) + pc;
      int off = ((pix << 7) + ((wave << 4) + lm) * 2) ^ ((pc & 7) << 4);
      *reinterpret_cast<ushort*>(ldsX + off) = f2bf(acc[f][r]);
    }
  }
  __syncthreads();

  // phase 2: mix MFMA (A from ldsX, B = wm)
  f4 acc2[16];
#pragma unroll
  for (int f = 0; f < 16; f++) acc2[f] = (f4){0.f, 0.f, 0.f, 0.f};
#pragma unroll
  for (int s = 0; s < 2; s++) {
    int kbyte = ((s << 5) + (lk << 3)) << 1;
#pragma unroll
    for (int f = 0; f < 16; f++) {
      int off = ((((f << 4) + lm) << 7) + kbyte) ^ ((lm & 7) << 4);
      bf8 a = *reinterpret_cast<const bf8*>(ldsX + off);
      acc2[f] = __builtin_amdgcn_mfma_f32_16x16x32_bf16(a, wm[s], acc2[f], 0, 0, 0);
    }
  }
  __syncthreads();

  // epilogue: quartered transpose via ldsS -> NHWC bf16 global
  float* ldsf = reinterpret_cast<float*>(ldsS);
  for (int q = 0; q < 4; q++) {
    if (q) __syncthreads();
#pragma unroll
    for (int fr = 0; fr < 4; fr++) {
      int f = q * 4 + fr;
      int co = (wave << 4) + lm;
#pragma unroll
      for (int r = 0; r < 4; r++) {
        int p = (lk << 2) + r;
        ldsf[fr * 1024 + p * 64 + (co ^ ((p & 12) << 2))] = acc2[f][r];
      }
    }
    __syncthreads();
#pragma unroll
    for (int i = 0; i < 2; i++) {
      int q2 = i * 256 + tid;
      int co8 = q2 & 7, p = (q2 >> 3) & 15, fr = q2 >> 7;
      int cb = (co8 * 8) ^ ((p & 12) << 2);
      f4 v0 = *reinterpret_cast<f4*>(&ldsf[fr * 1024 + p * 64 + cb]);
      f4 v1 = *reinterpret_cast<f4*>(&ldsf[fr * 1024 + p * 64 + cb + 4]);
      float vv[8] = {v0[0], v0[1], v0[2], v0[3], v1[0], v1[1], v1[2], v1[3]};
      union { ushort us[8]; int4 i4; } pk;
#pragma unroll
      for (int j = 0; j < 8; j++) pk.us[j] = f2bf(vv[j]);
      *reinterpret_cast<int4*>(
          out + (((size_t)b * H + h0 + q * 4 + fr) * W + w0 + p) * 64 + co8 * 8) = pk.i4;
    }
  }
}

// ---------------- depthwise 3x3 + GAP (NHWC bf16 in) ----------------
__global__ __launch_bounds__(256) void dwgap_k(
    const ushort* __restrict__ x1, const float* __restrict__ dww,
    float* __restrict__ pooled) {
  int c = threadIdx.x & 63;
  int q = threadIdx.x >> 6;
  int seg = blockIdx.x * 4 + q;  // 0..1023
  int row = seg >> 2;
  int wbase = (seg & 3) * 64;
  int b = blockIdx.y;
  float wv[9];
#pragma unroll
  for (int t = 0; t < 9; t++) wv[t] = dww[c * 9 + t];

  auto ld = [&](int hh, int ww) -> float {
    if (hh < 0 || hh >= H || ww < 0 || ww >= W) return 0.f;
    return bf2f(x1[(((size_t)b * H + hh) * W + ww) * 64 + c]);
  };
  float v[3][3];
#pragma unroll
  for (int dy = 0; dy < 3; dy++) {
    v[dy][0] = ld(row + dy - 1, wbase - 1);
    v[dy][1] = ld(row + dy - 1, wbase);
  }
  float acc = 0.f;
  for (int i = 0; i < 64; i++) {
    int w = wbase + i;
#pragma unroll
    for (int dy = 0; dy < 3; dy++) v[dy][2] = ld(row + dy - 1, w + 1);
    float s = 0.f;
#pragma unroll
    for (int dy = 0; dy < 3; dy++)
#pragma unroll
      for (int dx = 0; dx < 3; dx++) s += v[dy][dx] * wv[dy * 3 + dx];
    acc += s;
#pragma unroll
    for (int dy = 0; dy < 3; dy++) { v[dy][0] = v[dy][1]; v[dy][1] = v[dy][2]; }
  }
  atomicAdd(&pooled[b * 64 + c], acc);
}

// ---------------- MLP + softmax + blend -> Wm in B-fragment layout ----------------
__global__ void mlp_k(const float* __restrict__ pooled, const float* __restrict__ dwb,
                      const float* __restrict__ c1w, const float* __restrict__ c1b,
                      const float* __restrict__ c2w, const float* __restrict__ c2b,
                      const float* __restrict__ basep, ushort* __restrict__ wmf) {
  int b = blockIdx.x;
  int t = threadIdx.x;  // 64 threads
  __shared__ float pm[64], p1[64], p2[16];
  pm[t] = pooled[b * 64 + t] * (1.f / HWc) + dwb[t];
  __syncthreads();
  float a = c1b[t];
  for (int ci = 0; ci < 64; ci++) a += pm[ci] * c1w[t * 64 + ci];
  p1[t] = fmaxf(a, 0.f);
  __syncthreads();
  if (t < N) {
    float a2 = c2b[t];
    for (int ci = 0; ci < 64; ci++) a2 += p1[ci] * c2w[t * 64 + ci];
    p2[t] = a2;
  }
  __syncthreads();
  float m = -1e30f;
  for (int n = 0; n < N; n++) m = fmaxf(m, p2[n]);
  float e[N], s = 0.f;
  for (int n = 0; n < N; n++) { e[n] = expf(p2[n] - m); s += e[n]; }
  float inv = 1.f / s;
  // wmf[b][(s2*4+cf)*64+lane][j] = Wm[k][l], k = s2*32+(lane>>4)*8+j, l = cf*16+(lane&15)
  for (int idx = t; idx < 4096; idx += 64) {
    int j = idx & 7, lane = (idx >> 3) & 63, cf = (idx >> 9) & 3, s2 = idx >> 11;
    int k = (s2 << 5) + ((lane >> 4) << 3) + j;
    int l = (cf << 4) + (lane & 15);
    float acc = 0.f;
    for (int n = 0; n < N; n++) acc += e[n] * inv * basep[n * 4096 + k * 64 + l];
    wmf[(size_t)b * 4096 + idx] = f2bf(acc);
  }
}

__global__ void zero_k(float* p, int n) {
  int i = blockIdx.x * 256 + threadIdx.x;
  if (i < n) p[i] = 0.f;
}

extern "C" void kernel_launch(void* const* d_in, const int* in_sizes, int n_in,
                              void* d_out, int out_size, void* d_ws, size_t ws_size,
                              hipStream_t stream) {
  const float* x       = (const float*)d_in[0];
  const float* ln_g    = (const float*)d_in[1];
  const float* ln_b    = (const float*)d_in[2];
  const float* conv3_w = (const float*)d_in[3];
  const float* conv3_b = (const float*)d_in[4];
  const float* dw_w    = (const float*)d_in[5];
  const float* dw_b    = (const float*)d_in[6];
  const float* c1_w    = (const float*)d_in[7];
  const float* c1_b    = (const float*)d_in[8];
  const float* c2_w    = (const float*)d_in[9];
  const float* c2_b    = (const float*)d_in[10];
  const float* basep   = (const float*)d_in[11];
  const float* up_w    = (const float*)d_in[12];
  const float* up_b    = (const float*)d_in[13];
  const float* down_w  = (const float*)d_in[14];
  const float* down_b  = (const float*)d_in[15];
  float* out = (float*)d_out;

  char* wsb = (char*)d_ws;
  size_t big = (size_t)B * HWc * 64 * sizeof(ushort);  // 67,108,864
  ushort* bufA   = (ushort*)wsb;
  ushort* bufB   = (ushort*)(wsb + big);
  ushort* wfrags = (ushort*)(wsb + 2 * big);
  ushort* wmfrag = (ushort*)(wsb + 2 * big + 3 * 36864 * 2);
  float*  pooled = (float*)(wsb + 2 * big + 3 * 36864 * 2 + 8 * 4096 * 2);

  prep_w<<<54, 256, 0, stream>>>(conv3_w, up_w, down_w, wfrags);
  zero_k<<<2, 256, 0, stream>>>(pooled, B * C);
  // 1. LN: x -> bufA (NHWC bf16)
  ln_k<<<dim3(HWc / 256, B), 256, 0, stream>>>(x, ln_g, ln_b, bufA);
  // 2. conv3 + GELU: bufA -> bufB (x1)
  conv_mfma<1, 0><<<dim3(16, 16, B), 256, 0, stream>>>(
      bufA, wfrags + 0 * 36864, conv3_b, nullptr, bufB, nullptr);
  // 3. dw + GAP: bufB -> pooled
  dwgap_k<<<dim3(256, B), 256, 0, stream>>>(bufB, dw_w, pooled);
  // 4. MLP + blend: pooled -> wmfrag
  mlp_k<<<B, 64, 0, stream>>>(pooled, dw_b, c1_w, c1_b, c2_w, c2_b, basep, wmfrag);
  // 5+6. fused up conv + mix: bufB -> bufA (xm2, NHWC bf16)
  upmix_mfma<<<dim3(16, 16, B), 256, 0, stream>>>(
      bufB, wfrags + 1 * 36864, up_b, wmfrag, bufA);
  // 7. down conv + residual: bufA -> out (NCHW fp32)
  conv_mfma<0, 1><<<dim3(16, 16, B), 256, 0, stream>>>(
      bufA, wfrags + 2 * 36864, down_b, x, nullptr, out);
}

// Round 9
// 376.768 us; speedup vs baseline: 4.6518x; 1.0729x over previous
//
#include <hip/hip_runtime.h>
#include <math.h>

constexpr int B = 8, C = 64, H = 256, W = 256, HWc = H * W, N = 10;

typedef short bf8 __attribute__((ext_vector_type(8)));    // 8 x bf16 (4 VGPR)
typedef float f4  __attribute__((ext_vector_type(4)));    // MFMA accum
typedef unsigned short ushort;

__device__ __forceinline__ ushort f2bf(float f) {
  unsigned u = __builtin_bit_cast(unsigned, f);
  unsigned r = (u + 0x7fffu + ((u >> 16) & 1u)) >> 16;
  return (ushort)r;
}

// ---------------- LayerNorm: NCHW fp32 -> NHWC bf16 ----------------
__global__ __launch_bounds__(256) void ln_k(
    const float* __restrict__ x, const float* __restrict__ g,
    const float* __restrict__ bt, ushort* __restrict__ xn) {
  int pix = blockIdx.x * 256 + threadIdx.x;
  int b = blockIdx.y;
  const float* xp = x + (size_t)b * C * HWc + pix;
  float v[64];
  float s = 0.f, s2 = 0.f;
#pragma unroll
  for (int c = 0; c < 64; c++) {
    v[c] = xp[(size_t)c * HWc];
    s += v[c]; s2 += v[c] * v[c];
  }
  float mu = s * (1.f / 64);
  float var = s2 * (1.f / 64) - mu * mu;
  float rstd = rsqrtf(var + 1e-5f);
  ushort* op = xn + ((size_t)b * HWc + pix) * 64;
#pragma unroll
  for (int ch = 0; ch < 8; ch++) {
    union { ushort us[8]; int4 v4; } pk;
#pragma unroll
    for (int j = 0; j < 8; j++) {
      int c = ch * 8 + j;
      pk.us[j] = f2bf((v[c] - mu) * rstd * g[c] + bt[c]);
    }
    *reinterpret_cast<int4*>(op + ch * 8) = pk.v4;
  }
}

// ---------------- weight prep: OIHW fp32 -> MFMA fragment layout bf16 ----------------
__global__ void prep_w(const float* __restrict__ w3, const float* __restrict__ wu,
                       const float* __restrict__ wd, ushort* __restrict__ frags) {
  int idx = blockIdx.x * 256 + threadIdx.x;
  if (idx >= 3 * 4608) return;
  int conv = idx / 4608, r = idx % 4608;
  int s = r >> 8, cf = (r >> 6) & 3, lane = r & 63;
  const float* w = (conv == 0) ? w3 : (conv == 1) ? wu : wd;
  int co = (cf << 4) + (lane & 15);
  int tap = s >> 1;
  ushort* o = frags + conv * 36864 + ((size_t)r) * 8;
#pragma unroll
  for (int j = 0; j < 8; j++) {
    int ci = ((s & 1) << 5) + ((lane >> 4) << 3) + j;
    o[j] = f2bf(w[(co * 64 + ci) * 9 + tap]);
  }
}

// ======== staging split into load-early / write-late (T14) ========
struct Stg { int4 v[6]; };

__device__ __forceinline__ void stage_load(
    Stg& s, const ushort* __restrict__ in, int b, int h0, int w0,
    int ch2, int tid) {
#pragma unroll
  for (int it = 0; it < 6; it++) {
    int idx = it * 256 + tid;
    int4 v = make_int4(0, 0, 0, 0);
    if (idx < 1296) {
      int pix = idx >> 2, ch = idx & 3;
      int r = pix / 18, c = pix % 18;
      int gh = h0 + r - 1, gw = w0 + c - 1;
      if (gh >= 0 && gh < H && gw >= 0 && gw < W)
        v = *reinterpret_cast<const int4*>(
            in + (((size_t)b * H + gh) * W + gw) * 64 + ch2 * 32 + ch * 8);
    }
    s.v[it] = v;
  }
}

__device__ __forceinline__ void stage_write(const Stg& s, char* lds, int tid) {
#pragma unroll
  for (int it = 0; it < 6; it++) {
    int idx = it * 256 + tid;
    if (idx < 1296) {
      int pix = idx >> 2, ch = idx & 3;
      int c = pix % 18;
      int off = ((pix << 6) + (ch << 4)) ^ (((c >> 1) & 3) << 4);
      *reinterpret_cast<int4*>(lds + off) = s.v[it];
    }
  }
}

// compute one ci-half (3 dx groups); acc[f] += conv contributions
__device__ __forceinline__ void compute_half(
    const char* lds, const bf8* __restrict__ wf, int ch2,
    int wave, int lm, int lk, f4 (&acc)[16]) {
#pragma unroll
  for (int dx = 0; dx < 3; dx++) {
    bf8 wb3[3];
#pragma unroll
    for (int dy = 0; dy < 3; dy++) {
      int s = ((dy * 3 + dx) << 1) | ch2;
      wb3[dy] = wf[(s * 4 + wave) * 64 + (lk << 4) + lm];
    }
    int lc = lm + dx;
    int swz = ((lc >> 1) & 3) << 4;
    bf8 a[18];
#pragma unroll
    for (int r = 0; r < 18; r++) {
      int off = (((r * 18 + lc) << 6) + (lk << 4)) ^ swz;
      a[r] = *reinterpret_cast<const bf8*>(lds + off);
    }
#pragma unroll
    for (int dy = 0; dy < 3; dy++)
#pragma unroll
      for (int f = 0; f < 16; f++)
        acc[f] = __builtin_amdgcn_mfma_f32_16x16x32_bf16(a[f + dy], wb3[dy], acc[f], 0, 0, 0);
  }
}

// per-channel-slice partial reduce -> one atomic per channel. tid<64 handles ch c=tid.
__device__ __forceinline__ void red_at(
    float* ldsf, const float (&a)[8], float* __restrict__ stats9,
    int k, int b, int tid) {
  __syncthreads();
#pragma unroll
  for (int j = 0; j < 8; j++) ldsf[tid * 8 + j] = a[j];
  __syncthreads();
  if (tid < 64) {
    int grp = tid >> 3, j = tid & 7;
    float s = 0.f;
#pragma unroll
    for (int kk = 0; kk < 32; kk++) s += ldsf[(kk * 8 + grp) * 8 + j];
    atomicAdd(&stats9[(b * 64 + tid) * 9 + k], s);
  }
}

// ---------------- MFMA implicit-GEMM 3x3 conv ----------------
// in: NHWC bf16. OM=0: out NHWC bf16 (+GELU if ACT). OM=1: out NCHW fp32 + residual.
// DOST: accumulate dwconv-GAP stats (S, edge sums, corners) from post-GELU values.
// launch_bounds (256,2): proven no-spill point. NEVER raise the min-waves arg (R6: 2.8GB spill).
template <int ACT, int OM, int DOST>
__global__ __launch_bounds__(256, 2) void conv_mfma(
    const ushort* __restrict__ in, const ushort* __restrict__ wfrag,
    const float* __restrict__ bias, const float* __restrict__ resid,
    ushort* __restrict__ outb, float* __restrict__ outf,
    float* __restrict__ stats9) {
  __shared__ char lds[2 * 20736];  // double-buffered halves; epilogue reuses first 16 KB
  char* ldsA = lds;
  char* ldsB = lds + 20736;
  int tid = threadIdx.x;
  int b = blockIdx.z;
  int h0 = blockIdx.y * 16, w0 = blockIdx.x * 16;
  int wave = tid >> 6, lane = tid & 63;
  int lm = lane & 15, lk = lane >> 4;
  const bf8* wf = reinterpret_cast<const bf8*>(wfrag);

  f4 acc[16];
  {
    float bv = bias[(wave << 4) + lm];
    f4 ini = {bv, bv, bv, bv};
#pragma unroll
    for (int f = 0; f < 16; f++) acc[f] = ini;
  }

  // pipelined main loop: load0 -> write0 -> sync -> load1 | compute0 -> write1 -> sync -> compute1
  {
    Stg s0, s1;
    stage_load(s0, in, b, h0, w0, 0, tid);
    stage_write(s0, ldsA, tid);
    __syncthreads();
    stage_load(s1, in, b, h0, w0, 1, tid);   // in flight under compute_half(A)
    compute_half(ldsA, wf, 0, wave, lm, lk, acc);
    stage_write(s1, ldsB, tid);
    __syncthreads();
    compute_half(ldsB, wf, 1, wave, lm, lk, acc);
  }

  float* ldsf = reinterpret_cast<float*>(ldsA);
  if (OM == 0) {
    float s8[8], r08[8], rh8[8], c08[8], cw8[8];
    if (DOST) {
#pragma unroll
      for (int j = 0; j < 8; j++) { s8[j] = 0.f; r08[j] = 0.f; rh8[j] = 0.f; c08[j] = 0.f; cw8[j] = 0.f; }
    }
    bool top = (blockIdx.y == 0), bot = (blockIdx.y == 15);
    bool lef = (blockIdx.x == 0), rig = (blockIdx.x == 15);
    // 4 quarters of 4 pixel-rows: 4*16 px * 64 co * 4B = 16 KB
    for (int q = 0; q < 4; q++) {
      __syncthreads();   // also covers ldsA reuse after main loop
#pragma unroll
      for (int fr = 0; fr < 4; fr++) {
        int f = q * 4 + fr;
        int co = (wave << 4) + lm;
#pragma unroll
        for (int r = 0; r < 4; r++) {
          int p = (lk << 2) + r;
          ldsf[fr * 1024 + p * 64 + (co ^ ((p & 12) << 2))] = acc[f][r];
        }
      }
      __syncthreads();
#pragma unroll
      for (int i = 0; i < 2; i++) {
        int q2 = i * 256 + tid;               // 0..511
        int co8 = q2 & 7, p = (q2 >> 3) & 15, fr = q2 >> 7;
        int cb = (co8 * 8) ^ ((p & 12) << 2);
        f4 v0 = *reinterpret_cast<f4*>(&ldsf[fr * 1024 + p * 64 + cb]);
        f4 v1 = *reinterpret_cast<f4*>(&ldsf[fr * 1024 + p * 64 + cb + 4]);
        float vv[8] = {v0[0], v0[1], v0[2], v0[3], v1[0], v1[1], v1[2], v1[3]};
        union { ushort us[8]; int4 i4; } pk;
#pragma unroll
        for (int j = 0; j < 8; j++) {
          float v = vv[j];
          if (ACT) v = 0.5f * v * (1.f + erff(v * 0.70710678118654752f));
          if (DOST) {
            int rowg = q * 4 + fr;
            s8[j] += v;
            if (top && rowg == 0)  r08[j] += v;
            if (bot && rowg == 15) rh8[j] += v;
            if (lef && p == 0)     c08[j] += v;
            if (rig && p == 15)    cw8[j] += v;
            int cch = co8 * 8 + j;
            if (top && lef && rowg == 0 && p == 0)
              atomicAdd(&stats9[(b * 64 + cch) * 9 + 5], v);   // X00
            if (top && rig && rowg == 0 && p == 15)
              atomicAdd(&stats9[(b * 64 + cch) * 9 + 6], v);   // X0w
            if (bot && lef && rowg == 15 && p == 0)
              atomicAdd(&stats9[(b * 64 + cch) * 9 + 7], v);   // Xh0
            if (bot && rig && rowg == 15 && p == 15)
              atomicAdd(&stats9[(b * 64 + cch) * 9 + 8], v);   // Xhw
          }
          pk.us[j] = f2bf(v);
        }
        *reinterpret_cast<int4*>(
            outb + (((size_t)b * H + h0 + q * 4 + fr) * W + w0 + p) * 64 + co8 * 8) = pk.i4;
      }
    }
    if (DOST) {
      red_at(ldsf, s8, stats9, 0, b, tid);
      if (top) red_at(ldsf, r08, stats9, 1, b, tid);
      if (bot) red_at(ldsf, rh8, stats9, 2, b, tid);
      if (lef) red_at(ldsf, c08, stats9, 3, b, tid);
      if (rig) red_at(ldsf, cw8, stats9, 4, b, tid);
    }
  } else {
    // NCHW fp32 + residual; 4 quarters of 16 co (wave q writes): 16*256*4B = 16 KB
    for (int q = 0; q < 4; q++) {
      __syncthreads();
      if (wave == q) {
#pragma unroll
        for (int f = 0; f < 16; f++) {
          int pxl = (f << 4) + (lk << 2);
          int pxs = pxl ^ ((lm & 7) << 2);
          *reinterpret_cast<f4*>(&ldsf[lm * 256 + pxs]) = acc[f];
        }
      }
      // prefetch this quarter's residual BEFORE the barrier (hides HBM latency)
      float4 rv[4];
#pragma unroll
      for (int i = 0; i < 4; i++) {
        int q2 = i * 256 + tid;
        int chunk = q2 & 63, co16 = q2 >> 6;
        int pq = chunk * 4;
        int co = q * 16 + co16;
        size_t o = ((size_t)(b * 64 + co)) * HWc +
                   (size_t)(h0 + (pq >> 4)) * W + w0 + (pq & 15);
        rv[i] = *reinterpret_cast<const float4*>(resid + o);
      }
      __syncthreads();
#pragma unroll
      for (int i = 0; i < 4; i++) {
        int q2 = i * 256 + tid;
        int chunk = q2 & 63, co16 = q2 >> 6;
        int pq = chunk * 4;
        int pxs = pq ^ ((co16 & 7) << 2);
        f4 v = *reinterpret_cast<f4*>(&ldsf[co16 * 256 + pxs]);
        int co = q * 16 + co16;
        size_t o = ((size_t)(b * 64 + co)) * HWc +
                   (size_t)(h0 + (pq >> 4)) * W + w0 + (pq & 15);
        float4 ov;
        ov.x = v[0] + rv[i].x; ov.y = v[1] + rv[i].y;
        ov.z = v[2] + rv[i].z; ov.w = v[3] + rv[i].w;
        *reinterpret_cast<float4*>(outf + o) = ov;
      }
    }
  }
}

// ---------------- fused up-conv + channel mix ----------------
__global__ __launch_bounds__(256, 2) void upmix_mfma(
    const ushort* __restrict__ in, const ushort* __restrict__ wfrag,
    const float* __restrict__ bias, const ushort* __restrict__ wmf,
    ushort* __restrict__ out) {
  __shared__ char ldsS[2 * 20736];   // DB stage halves / final epilogue quarter
  __shared__ char ldsX[32768];       // xm tile [pix][k] bf16, mix-swizzled
  char* ldsA = ldsS;
  char* ldsB = ldsS + 20736;
  int tid = threadIdx.x;
  int b = blockIdx.z;
  int h0 = blockIdx.y * 16, w0 = blockIdx.x * 16;
  int wave = tid >> 6, lane = tid & 63;
  int lm = lane & 15, lk = lane >> 4;
  const bf8* wf = reinterpret_cast<const bf8*>(wfrag);

  const bf8* wmb = reinterpret_cast<const bf8*>(wmf + (size_t)b * 4096);
  bf8 wm[2];
#pragma unroll
  for (int s = 0; s < 2; s++) wm[s] = wmb[(s * 4 + wave) * 64 + lane];

  f4 acc[16];
  {
    float bv = bias[(wave << 4) + lm];
    f4 ini = {bv, bv, bv, bv};
#pragma unroll
    for (int f = 0; f < 16; f++) acc[f] = ini;
  }

  {
    Stg s0, s1;
    stage_load(s0, in, b, h0, w0, 0, tid);
    stage_write(s0, ldsA, tid);
    __syncthreads();
    stage_load(s1, in, b, h0, w0, 1, tid);
    compute_half(ldsA, wf, 0, wave, lm, lk, acc);
    stage_write(s1, ldsB, tid);
    __syncthreads();
    compute_half(ldsB, wf, 1, wave, lm, lk, acc);
  }

  // scatter acc -> xm tile (bf16) in mix staging layout
#pragma unroll
  for (int f = 0; f < 16; f++) {
#pragma unroll
    for (int r = 0; r < 4; r++) {
      int pc = (lk << 2) + r;
      int pix = (f << 4) + pc;
      int off = ((pix << 7) + ((wave << 4) + lm) * 2) ^ ((pc & 7) << 4);
      *reinterpret_cast<ushort*>(ldsX + off) = f2bf(acc[f][r]);
    }
  }
  __syncthreads();

  f4 acc2[16];
#pragma unroll
  for (int f = 0; f < 16; f++) acc2[f] = (f4){0.f, 0.f, 0.f, 0.f};
#pragma unroll
  for (int s = 0; s < 2; s++) {
    int kbyte = ((s << 5) + (lk << 3)) << 1;
#pragma unroll
    for (int f = 0; f < 16; f++) {
      int off = ((((f << 4) + lm) << 7) + kbyte) ^ ((lm & 7) << 4);
      bf8 a = *reinterpret_cast<const bf8*>(ldsX + off);
      acc2[f] = __builtin_amdgcn_mfma_f32_16x16x32_bf16(a, wm[s], acc2[f], 0, 0, 0);
    }
  }

  float* ldsf = reinterpret_cast<float*>(ldsA);
  for (int q = 0; q < 4; q++) {
    __syncthreads();
#pragma unroll
    for (int fr = 0; fr < 4; fr++) {
      int f = q * 4 + fr;
      int co = (wave << 4) + lm;
#pragma unroll
      for (int r = 0; r < 4; r++) {
        int p = (lk << 2) + r;
        ldsf[fr * 1024 + p * 64 + (co ^ ((p & 12) << 2))] = acc2[f][r];
      }
    }
    __syncthreads();
#pragma unroll
    for (int i = 0; i < 2; i++) {
      int q2 = i * 256 + tid;
      int co8 = q2 & 7, p = (q2 >> 3) & 15, fr = q2 >> 7;
      int cb = (co8 * 8) ^ ((p & 12) << 2);
      f4 v0 = *reinterpret_cast<f4*>(&ldsf[fr * 1024 + p * 64 + cb]);
      f4 v1 = *reinterpret_cast<f4*>(&ldsf[fr * 1024 + p * 64 + cb + 4]);
      float vv[8] = {v0[0], v0[1], v0[2], v0[3], v1[0], v1[1], v1[2], v1[3]};
      union { ushort us[8]; int4 i4; } pk;
#pragma unroll
      for (int j = 0; j < 8; j++) pk.us[j] = f2bf(vv[j]);
      *reinterpret_cast<int4*>(
          out + (((size_t)b * H + h0 + q * 4 + fr) * W + w0 + p) * 64 + co8 * 8) = pk.i4;
    }
  }
}

// ---------------- MLP + softmax + blend (pooled reconstructed from stats) ----------------
// stats[b][c][k]: 0=S,1=R0(row0),2=Rh(rowH-1),3=C0(col0),4=Cw(colW-1),
//                 5=X00,6=X0w,7=Xh0,8=Xhw  (sums of post-GELU x1)
__global__ void mlp_k(const float* __restrict__ stats9, const float* __restrict__ dww,
                      const float* __restrict__ dwb,
                      const float* __restrict__ c1w, const float* __restrict__ c1b,
                      const float* __restrict__ c2w, const float* __restrict__ c2b,
                      const float* __restrict__ basep, ushort* __restrict__ wmf) {
  int b = blockIdx.x;
  int t = threadIdx.x;  // 64 threads
  __shared__ float pm[64], p1[64], p2[16];
  {
    const float* st = stats9 + (b * 64 + t) * 9;
    float S = st[0], R0 = st[1], Rh = st[2], C0 = st[3], Cw = st[4];
    float X00 = st[5], X0w = st[6], Xh0 = st[7], Xhw = st[8];
    float acc = 0.f;
#pragma unroll
    for (int ky = 0; ky < 3; ky++)
#pragma unroll
      for (int kx = 0; kx < 3; kx++) {
        float T = S;
        if (ky == 2) T -= R0;
        if (ky == 0) T -= Rh;
        if (kx == 2) T -= C0;
        if (kx == 0) T -= Cw;
        if (ky == 2 && kx == 2) T += X00;
        if (ky == 2 && kx == 0) T += X0w;
        if (ky == 0 && kx == 2) T += Xh0;
        if (ky == 0 && kx == 0) T += Xhw;
        acc += dww[t * 9 + ky * 3 + kx] * T;
      }
    pm[t] = acc * (1.f / HWc) + dwb[t];
  }
  __syncthreads();
  float a = c1b[t];
  for (int ci = 0; ci < 64; ci++) a += pm[ci] * c1w[t * 64 + ci];
  p1[t] = fmaxf(a, 0.f);
  __syncthreads();
  if (t < N) {
    float a2 = c2b[t];
    for (int ci = 0; ci < 64; ci++) a2 += p1[ci] * c2w[t * 64 + ci];
    p2[t] = a2;
  }
  __syncthreads();
  float m = -1e30f;
  for (int n = 0; n < N; n++) m = fmaxf(m, p2[n]);
  float e[N], s = 0.f;
  for (int n = 0; n < N; n++) { e[n] = expf(p2[n] - m); s += e[n]; }
  float inv = 1.f / s;
  for (int idx = t; idx < 4096; idx += 64) {
    int j = idx & 7, lane = (idx >> 3) & 63, cf = (idx >> 9) & 3, s2 = idx >> 11;
    int k = (s2 << 5) + ((lane >> 4) << 3) + j;
    int l = (cf << 4) + (lane & 15);
    float acc = 0.f;
    for (int n = 0; n < N; n++) acc += e[n] * inv * basep[n * 4096 + k * 64 + l];
    wmf[(size_t)b * 4096 + idx] = f2bf(acc);
  }
}

__global__ void zero_k(float* p, int n) {
  int i = blockIdx.x * 256 + threadIdx.x;
  if (i < n) p[i] = 0.f;
}

extern "C" void kernel_launch(void* const* d_in, const int* in_sizes, int n_in,
                              void* d_out, int out_size, void* d_ws, size_t ws_size,
                              hipStream_t stream) {
  const float* x       = (const float*)d_in[0];
  const float* ln_g    = (const float*)d_in[1];
  const float* ln_b    = (const float*)d_in[2];
  const float* conv3_w = (const float*)d_in[3];
  const float* conv3_b = (const float*)d_in[4];
  const float* dw_w    = (const float*)d_in[5];
  const float* dw_b    = (const float*)d_in[6];
  const float* c1_w    = (const float*)d_in[7];
  const float* c1_b    = (const float*)d_in[8];
  const float* c2_w    = (const float*)d_in[9];
  const float* c2_b    = (const float*)d_in[10];
  const float* basep   = (const float*)d_in[11];
  const float* up_w    = (const float*)d_in[12];
  const float* up_b    = (const float*)d_in[13];
  const float* down_w  = (const float*)d_in[14];
  const float* down_b  = (const float*)d_in[15];
  float* out = (float*)d_out;

  char* wsb = (char*)d_ws;
  size_t big = (size_t)B * HWc * 64 * sizeof(ushort);  // 67,108,864
  ushort* bufA   = (ushort*)wsb;
  ushort* bufB   = (ushort*)(wsb + big);
  ushort* wfrags = (ushort*)(wsb + 2 * big);
  ushort* wmfrag = (ushort*)(wsb + 2 * big + 3 * 36864 * 2);
  float*  stats  = (float*)(wsb + 2 * big + 3 * 36864 * 2 + 8 * 4096 * 2);  // 8*64*9

  prep_w<<<54, 256, 0, stream>>>(conv3_w, up_w, down_w, wfrags);
  zero_k<<<18, 256, 0, stream>>>(stats, B * 64 * 9);
  // 1. LN: x -> bufA (NHWC bf16)
  ln_k<<<dim3(HWc / 256, B), 256, 0, stream>>>(x, ln_g, ln_b, bufA);
  // 2. conv3 + GELU + dwgap-stats: bufA -> bufB (x1), stats
  conv_mfma<1, 0, 1><<<dim3(16, 16, B), 256, 0, stream>>>(
      bufA, wfrags + 0 * 36864, conv3_b, nullptr, bufB, nullptr, stats);
  // 3. MLP + blend (pooled from stats): -> wmfrag
  mlp_k<<<B, 64, 0, stream>>>(stats, dw_w, dw_b, c1_w, c1_b, c2_w, c2_b, basep, wmfrag);
  // 4. fused up conv + mix: bufB -> bufA (xm2, NHWC bf16)
  upmix_mfma<<<dim3(16, 16, B), 256, 0, stream>>>(
      bufB, wfrags + 1 * 36864, up_b, wmfrag, bufA);
  // 5. down conv + residual: bufA -> out (NCHW fp32)
  conv_mfma<0, 1, 0><<<dim3(16, 16, B), 256, 0, stream>>>(
      bufA, wfrags + 2 * 36864, down_b, x, nullptr, out, stats);
}

// Round 10
// 345.762 us; speedup vs baseline: 5.0690x; 1.0897x over previous
//
#include <hip/hip_runtime.h>
#include <math.h>

constexpr int B = 8, C = 64, H = 256, W = 256, HWc = H * W, N = 10;

typedef short bf8 __attribute__((ext_vector_type(8)));    // 8 x bf16 (4 VGPR)
typedef float f4  __attribute__((ext_vector_type(4)));    // MFMA accum
typedef unsigned short ushort;

__device__ __forceinline__ ushort f2bf(float f) {
  unsigned u = __builtin_bit_cast(unsigned, f);
  unsigned r = (u + 0x7fffu + ((u >> 16) & 1u)) >> 16;
  return (ushort)r;
}
__device__ __forceinline__ float bf2f(ushort h) {
  unsigned u = ((unsigned)h) << 16;
  return __builtin_bit_cast(float, u);
}

// ---------------- LayerNorm: NCHW fp32 -> NHWC bf16 ----------------
__global__ __launch_bounds__(256) void ln_k(
    const float* __restrict__ x, const float* __restrict__ g,
    const float* __restrict__ bt, ushort* __restrict__ xn) {
  int pix = blockIdx.x * 256 + threadIdx.x;
  int b = blockIdx.y;
  const float* xp = x + (size_t)b * C * HWc + pix;
  float v[64];
  float s = 0.f, s2 = 0.f;
#pragma unroll
  for (int c = 0; c < 64; c++) {
    v[c] = xp[(size_t)c * HWc];
    s += v[c]; s2 += v[c] * v[c];
  }
  float mu = s * (1.f / 64);
  float var = s2 * (1.f / 64) - mu * mu;
  float rstd = rsqrtf(var + 1e-5f);
  ushort* op = xn + ((size_t)b * HWc + pix) * 64;
#pragma unroll
  for (int ch = 0; ch < 8; ch++) {
    union { ushort us[8]; int4 v4; } pk;
#pragma unroll
    for (int j = 0; j < 8; j++) {
      int c = ch * 8 + j;
      pk.us[j] = f2bf((v[c] - mu) * rstd * g[c] + bt[c]);
    }
    *reinterpret_cast<int4*>(op + ch * 8) = pk.v4;
  }
}

// ---------------- weight prep: OIHW fp32 -> MFMA fragment layout bf16 ----------------
__global__ void prep_w(const float* __restrict__ w3, const float* __restrict__ wu,
                       const float* __restrict__ wd, ushort* __restrict__ frags) {
  int idx = blockIdx.x * 256 + threadIdx.x;
  if (idx >= 3 * 4608) return;
  int conv = idx / 4608, r = idx % 4608;
  int s = r >> 8, cf = (r >> 6) & 3, lane = r & 63;
  const float* w = (conv == 0) ? w3 : (conv == 1) ? wu : wd;
  int co = (cf << 4) + (lane & 15);
  int tap = s >> 1;
  ushort* o = frags + conv * 36864 + ((size_t)r) * 8;
#pragma unroll
  for (int j = 0; j < 8; j++) {
    int ci = ((s & 1) << 5) + ((lane >> 4) << 3) + j;
    o[j] = f2bf(w[(co * 64 + ci) * 9 + tap]);
  }
}

// ======== conv staging: single-buffer, proven R7 form ========
__device__ __forceinline__ void stage_half(
    char* lds, const ushort* __restrict__ in, int b, int h0, int w0,
    int ch2, int tid) {
  for (int idx = tid; idx < 18 * 18 * 4; idx += 256) {
    int pix = idx >> 2, ch = idx & 3;
    int r = pix / 18, c = pix % 18;
    int gh = h0 + r - 1, gw = w0 + c - 1;
    int4 v = make_int4(0, 0, 0, 0);
    if (gh >= 0 && gh < H && gw >= 0 && gw < W)
      v = *reinterpret_cast<const int4*>(
          in + (((size_t)b * H + gh) * W + gw) * 64 + ch2 * 32 + ch * 8);
    int off = ((pix << 6) + (ch << 4)) ^ (((c >> 1) & 3) << 4);
    *reinterpret_cast<int4*>(lds + off) = v;
  }
}

// compute one ci-half (3 dx groups); acc[f] += conv contributions
__device__ __forceinline__ void compute_half(
    const char* lds, const bf8* __restrict__ wf, int ch2,
    int wave, int lm, int lk, f4 (&acc)[16]) {
#pragma unroll
  for (int dx = 0; dx < 3; dx++) {
    bf8 wb3[3];
#pragma unroll
    for (int dy = 0; dy < 3; dy++) {
      int s = ((dy * 3 + dx) << 1) | ch2;
      wb3[dy] = wf[(s * 4 + wave) * 64 + (lk << 4) + lm];
    }
    int lc = lm + dx;
    int swz = ((lc >> 1) & 3) << 4;
    bf8 a[18];
#pragma unroll
    for (int r = 0; r < 18; r++) {
      int off = (((r * 18 + lc) << 6) + (lk << 4)) ^ swz;
      a[r] = *reinterpret_cast<const bf8*>(lds + off);
    }
#pragma unroll
    for (int dy = 0; dy < 3; dy++)
#pragma unroll
      for (int f = 0; f < 16; f++)
        acc[f] = __builtin_amdgcn_mfma_f32_16x16x32_bf16(a[f + dy], wb3[dy], acc[f], 0, 0, 0);
  }
}

// block-level per-channel reduce -> one atomic per channel.
// Thread tid's a[j] is a partial for channel (tid&7)*8+j. Transposed store: stride-1
// per lane (conflict-free); reducer thread t handles channel t.
__device__ __forceinline__ void red_at(
    float* ldsf, const float (&a)[8], float* __restrict__ stats9,
    int k, int b, int tid) {
  __syncthreads();
#pragma unroll
  for (int j = 0; j < 8; j++) ldsf[j * 256 + tid] = a[j];
  __syncthreads();
  if (tid < 64) {
    float s = 0.f;
#pragma unroll
    for (int kk = 0; kk < 32; kk++) s += ldsf[(tid & 7) * 256 + kk * 8 + (tid >> 3)];
    atomicAdd(&stats9[(b * 64 + tid) * 9 + k], s);
  }
}

// ---------------- MFMA implicit-GEMM 3x3 conv ----------------
// in: NHWC bf16. OM=0: out NHWC bf16 (+GELU if ACT). OM=1: out NCHW fp32 + residual.
// DOST: accumulate ONLY the full-tile channel sum S (stats k=0); edge/corner stats
// come from edge_k (R9 lesson: 40 stats VGPRs + staged prefetch regs => scratch spill,
// WRITE_SIZE 445MB). launch_bounds (256,2): proven no-spill point; never raise.
template <int ACT, int OM, int DOST>
__global__ __launch_bounds__(256, 2) void conv_mfma(
    const ushort* __restrict__ in, const ushort* __restrict__ wfrag,
    const float* __restrict__ bias, const float* __restrict__ resid,
    ushort* __restrict__ outb, float* __restrict__ outf,
    float* __restrict__ stats9) {
  __shared__ char lds[20736];  // stage half / epilogue reuse (16 KB)
  int tid = threadIdx.x;
  int b = blockIdx.z;
  int h0 = blockIdx.y * 16, w0 = blockIdx.x * 16;
  int wave = tid >> 6, lane = tid & 63;
  int lm = lane & 15, lk = lane >> 4;
  const bf8* wf = reinterpret_cast<const bf8*>(wfrag);

  f4 acc[16];
  {
    float bv = bias[(wave << 4) + lm];
    f4 ini = {bv, bv, bv, bv};
#pragma unroll
    for (int f = 0; f < 16; f++) acc[f] = ini;
  }

#pragma unroll
  for (int ch2 = 0; ch2 < 2; ch2++) {
    if (ch2) __syncthreads();   // all reads of previous half done
    stage_half(lds, in, b, h0, w0, ch2, tid);
    __syncthreads();
    compute_half(lds, wf, ch2, wave, lm, lk, acc);
  }

  float* ldsf = reinterpret_cast<float*>(lds);
  if (OM == 0) {
    float s8[8];
    if (DOST) {
#pragma unroll
      for (int j = 0; j < 8; j++) s8[j] = 0.f;
    }
    // 4 quarters of 4 pixel-rows: 4*16 px * 64 co * 4B = 16 KB
    for (int q = 0; q < 4; q++) {
      __syncthreads();
#pragma unroll
      for (int fr = 0; fr < 4; fr++) {
        int f = q * 4 + fr;
        int co = (wave << 4) + lm;
#pragma unroll
        for (int r = 0; r < 4; r++) {
          int p = (lk << 2) + r;
          ldsf[fr * 1024 + p * 64 + (co ^ ((p & 12) << 2))] = acc[f][r];
        }
      }
      __syncthreads();
#pragma unroll
      for (int i = 0; i < 2; i++) {
        int q2 = i * 256 + tid;               // 0..511
        int co8 = q2 & 7, p = (q2 >> 3) & 15, fr = q2 >> 7;
        int cb = (co8 * 8) ^ ((p & 12) << 2);
        f4 v0 = *reinterpret_cast<f4*>(&ldsf[fr * 1024 + p * 64 + cb]);
        f4 v1 = *reinterpret_cast<f4*>(&ldsf[fr * 1024 + p * 64 + cb + 4]);
        float vv[8] = {v0[0], v0[1], v0[2], v0[3], v1[0], v1[1], v1[2], v1[3]};
        union { ushort us[8]; int4 i4; } pk;
#pragma unroll
        for (int j = 0; j < 8; j++) {
          float v = vv[j];
          if (ACT) v = 0.5f * v * (1.f + erff(v * 0.70710678118654752f));
          if (DOST) s8[j] += v;
          pk.us[j] = f2bf(v);
        }
        *reinterpret_cast<int4*>(
            outb + (((size_t)b * H + h0 + q * 4 + fr) * W + w0 + p) * 64 + co8 * 8) = pk.i4;
      }
    }
    if (DOST) red_at(ldsf, s8, stats9, 0, b, tid);
  } else {
    // NCHW fp32 + residual; 4 quarters of 16 co (wave q writes): 16*256*4B = 16 KB
    for (int q = 0; q < 4; q++) {
      __syncthreads();
      if (wave == q) {
#pragma unroll
        for (int f = 0; f < 16; f++) {
          int pxl = (f << 4) + (lk << 2);
          int pxs = pxl ^ ((lm & 7) << 2);
          *reinterpret_cast<f4*>(&ldsf[lm * 256 + pxs]) = acc[f];
        }
      }
      // prefetch this quarter's residual BEFORE the barrier (hides HBM latency)
      float4 rv[4];
#pragma unroll
      for (int i = 0; i < 4; i++) {
        int q2 = i * 256 + tid;
        int chunk = q2 & 63, co16 = q2 >> 6;
        int pq = chunk * 4;
        int co = q * 16 + co16;
        size_t o = ((size_t)(b * 64 + co)) * HWc +
                   (size_t)(h0 + (pq >> 4)) * W + w0 + (pq & 15);
        rv[i] = *reinterpret_cast<const float4*>(resid + o);
      }
      __syncthreads();
#pragma unroll
      for (int i = 0; i < 4; i++) {
        int q2 = i * 256 + tid;
        int chunk = q2 & 63, co16 = q2 >> 6;
        int pq = chunk * 4;
        int pxs = pq ^ ((co16 & 7) << 2);
        f4 v = *reinterpret_cast<f4*>(&ldsf[co16 * 256 + pxs]);
        int co = q * 16 + co16;
        size_t o = ((size_t)(b * 64 + co)) * HWc +
                   (size_t)(h0 + (pq >> 4)) * W + w0 + (pq & 15);
        float4 ov;
        ov.x = v[0] + rv[i].x; ov.y = v[1] + rv[i].y;
        ov.z = v[2] + rv[i].z; ov.w = v[3] + rv[i].w;
        *reinterpret_cast<float4*>(outf + o) = ov;
      }
    }
  }
}

// ---------------- boundary-strip stats (k=1..8) from x1 ----------------
// R0/Rh/C0/Cw edge sums + 4 corners; replaces 32 VGPRs of in-conv stats with a
// ~1MB coalesced read. Plain stores (sole writer of k=1..8).
__global__ __launch_bounds__(256) void edge_k(const ushort* __restrict__ x1,
                                              float* __restrict__ stats9) {
  int b = blockIdx.x;
  int t = threadIdx.x;
  __shared__ float red[256];
  const size_t bb = (size_t)b * HWc * 64;
#pragma unroll
  for (int st = 0; st < 4; st++) {
    float s = 0.f;
    for (int i = 0; i < 64; i++) {
      int idx = i * 256 + t;                 // 16384 = 256 px * 64 ch, coalesced
      int pix = idx >> 6, c = idx & 63;
      size_t off;
      if (st == 0)      off = ((size_t)pix) * 64 + c;                       // row 0
      else if (st == 1) off = ((size_t)(H - 1) * W + pix) * 64 + c;         // row H-1
      else if (st == 2) off = ((size_t)pix * W) * 64 + c;                   // col 0
      else              off = ((size_t)pix * W + (W - 1)) * 64 + c;         // col W-1
      s += bf2f(x1[bb + off]);
    }
    red[t] = s;                              // t = q*... : channel t&63, partial t>>6
    __syncthreads();
    if (t < 64) {
      // channel t partials sit at red[t], red[t+64], red[t+128], red[t+192]?
      // idx&63==c fixed per thread: c = t&63; partial index = t>>6.
      float v = red[t] + red[t + 64] + red[t + 128] + red[t + 192];
      stats9[(b * 64 + t) * 9 + 1 + st] = v;
    }
    __syncthreads();
  }
  if (t < 64) {
    stats9[(b * 64 + t) * 9 + 5] = bf2f(x1[bb + t]);                                  // X00
    stats9[(b * 64 + t) * 9 + 6] = bf2f(x1[bb + ((size_t)(W - 1)) * 64 + t]);         // X0w
    stats9[(b * 64 + t) * 9 + 7] = bf2f(x1[bb + ((size_t)(H - 1) * W) * 64 + t]);     // Xh0
    stats9[(b * 64 + t) * 9 + 8] = bf2f(x1[bb + ((size_t)(H - 1) * W + W - 1) * 64 + t]); // Xhw
  }
}

// ---------------- fused up-conv + channel mix ----------------
__global__ __launch_bounds__(256, 2) void upmix_mfma(
    const ushort* __restrict__ in, const ushort* __restrict__ wfrag,
    const float* __restrict__ bias, const ushort* __restrict__ wmf,
    ushort* __restrict__ out) {
  __shared__ char ldsS[20736];   // stage half / final epilogue quarter
  __shared__ char ldsX[32768];   // xm tile [pix][k] bf16, mix-swizzled
  int tid = threadIdx.x;
  int b = blockIdx.z;
  int h0 = blockIdx.y * 16, w0 = blockIdx.x * 16;
  int wave = tid >> 6, lane = tid & 63;
  int lm = lane & 15, lk = lane >> 4;
  const bf8* wf = reinterpret_cast<const bf8*>(wfrag);

  const bf8* wmb = reinterpret_cast<const bf8*>(wmf + (size_t)b * 4096);
  bf8 wm[2];
#pragma unroll
  for (int s = 0; s < 2; s++) wm[s] = wmb[(s * 4 + wave) * 64 + lane];

  f4 acc[16];
  {
    float bv = bias[(wave << 4) + lm];
    f4 ini = {bv, bv, bv, bv};
#pragma unroll
    for (int f = 0; f < 16; f++) acc[f] = ini;
  }

#pragma unroll
  for (int ch2 = 0; ch2 < 2; ch2++) {
    if (ch2) __syncthreads();
    stage_half(ldsS, in, b, h0, w0, ch2, tid);
    __syncthreads();
    compute_half(ldsS, wf, ch2, wave, lm, lk, acc);
  }

  // scatter acc -> xm tile (bf16) in mix staging layout
#pragma unroll
  for (int f = 0; f < 16; f++) {
#pragma unroll
    for (int r = 0; r < 4; r++) {
      int pc = (lk << 2) + r;
      int pix = (f << 4) + pc;
      int off = ((pix << 7) + ((wave << 4) + lm) * 2) ^ ((pc & 7) << 4);
      *reinterpret_cast<ushort*>(ldsX + off) = f2bf(acc[f][r]);
    }
  }
  __syncthreads();

  f4 acc2[16];
#pragma unroll
  for (int f = 0; f < 16; f++) acc2[f] = (f4){0.f, 0.f, 0.f, 0.f};
#pragma unroll
  for (int s = 0; s < 2; s++) {
    int kbyte = ((s << 5) + (lk << 3)) << 1;
#pragma unroll
    for (int f = 0; f < 16; f++) {
      int off = ((((f << 4) + lm) << 7) + kbyte) ^ ((lm & 7) << 4);
      bf8 a = *reinterpret_cast<const bf8*>(ldsX + off);
      acc2[f] = __builtin_amdgcn_mfma_f32_16x16x32_bf16(a, wm[s], acc2[f], 0, 0, 0);
    }
  }

  float* ldsf = reinterpret_cast<float*>(ldsS);
  for (int q = 0; q < 4; q++) {
    __syncthreads();
#pragma unroll
    for (int fr = 0; fr < 4; fr++) {
      int f = q * 4 + fr;
      int co = (wave << 4) + lm;
#pragma unroll
      for (int r = 0; r < 4; r++) {
        int p = (lk << 2) + r;
        ldsf[fr * 1024 + p * 64 + (co ^ ((p & 12) << 2))] = acc2[f][r];
      }
    }
    __syncthreads();
#pragma unroll
    for (int i = 0; i < 2; i++) {
      int q2 = i * 256 + tid;
      int co8 = q2 & 7, p = (q2 >> 3) & 15, fr = q2 >> 7;
      int cb = (co8 * 8) ^ ((p & 12) << 2);
      f4 v0 = *reinterpret_cast<f4*>(&ldsf[fr * 1024 + p * 64 + cb]);
      f4 v1 = *reinterpret_cast<f4*>(&ldsf[fr * 1024 + p * 64 + cb + 4]);
      float vv[8] = {v0[0], v0[1], v0[2], v0[3], v1[0], v1[1], v1[2], v1[3]};
      union { ushort us[8]; int4 i4; } pk;
#pragma unroll
      for (int j = 0; j < 8; j++) pk.us[j] = f2bf(vv[j]);
      *reinterpret_cast<int4*>(
          out + (((size_t)b * H + h0 + q * 4 + fr) * W + w0 + p) * 64 + co8 * 8) = pk.i4;
    }
  }
}

// ---------------- MLP + softmax + blend (pooled reconstructed from stats) ----------------
// stats[b][c][k]: 0=S,1=R0,2=Rh,3=C0,4=Cw,5=X00,6=X0w,7=Xh0,8=Xhw (post-GELU x1 sums)
__global__ void mlp_k(const float* __restrict__ stats9, const float* __restrict__ dww,
                      const float* __restrict__ dwb,
                      const float* __restrict__ c1w, const float* __restrict__ c1b,
                      const float* __restrict__ c2w, const float* __restrict__ c2b,
                      const float* __restrict__ basep, ushort* __restrict__ wmf) {
  int b = blockIdx.x;
  int t = threadIdx.x;  // 64 threads
  __shared__ float pm[64], p1[64], p2[16];
  {
    const float* st = stats9 + (b * 64 + t) * 9;
    float S = st[0], R0 = st[1], Rh = st[2], C0 = st[3], Cw = st[4];
    float X00 = st[5], X0w = st[6], Xh0 = st[7], Xhw = st[8];
    float acc = 0.f;
#pragma unroll
    for (int ky = 0; ky < 3; ky++)
#pragma unroll
      for (int kx = 0; kx < 3; kx++) {
        float T = S;
        if (ky == 2) T -= R0;
        if (ky == 0) T -= Rh;
        if (kx == 2) T -= C0;
        if (kx == 0) T -= Cw;
        if (ky == 2 && kx == 2) T += X00;
        if (ky == 2 && kx == 0) T += X0w;
        if (ky == 0 && kx == 2) T += Xh0;
        if (ky == 0 && kx == 0) T += Xhw;
        acc += dww[t * 9 + ky * 3 + kx] * T;
      }
    pm[t] = acc * (1.f / HWc) + dwb[t];
  }
  __syncthreads();
  float a = c1b[t];
  for (int ci = 0; ci < 64; ci++) a += pm[ci] * c1w[t * 64 + ci];
  p1[t] = fmaxf(a, 0.f);
  __syncthreads();
  if (t < N) {
    float a2 = c2b[t];
    for (int ci = 0; ci < 64; ci++) a2 += p1[ci] * c2w[t * 64 + ci];
    p2[t] = a2;
  }
  __syncthreads();
  float m = -1e30f;
  for (int n = 0; n < N; n++) m = fmaxf(m, p2[n]);
  float e[N], s = 0.f;
  for (int n = 0; n < N; n++) { e[n] = expf(p2[n] - m); s += e[n]; }
  float inv = 1.f / s;
  for (int idx = t; idx < 4096; idx += 64) {
    int j = idx & 7, lane = (idx >> 3) & 63, cf = (idx >> 9) & 3, s2 = idx >> 11;
    int k = (s2 << 5) + ((lane >> 4) << 3) + j;
    int l = (cf << 4) + (lane & 15);
    float acc = 0.f;
    for (int n = 0; n < N; n++) acc += e[n] * inv * basep[n * 4096 + k * 64 + l];
    wmf[(size_t)b * 4096 + idx] = f2bf(acc);
  }
}

__global__ void zero_k(float* p, int n) {
  int i = blockIdx.x * 256 + threadIdx.x;
  if (i < n) p[i] = 0.f;
}

extern "C" void kernel_launch(void* const* d_in, const int* in_sizes, int n_in,
                              void* d_out, int out_size, void* d_ws, size_t ws_size,
                              hipStream_t stream) {
  const float* x       = (const float*)d_in[0];
  const float* ln_g    = (const float*)d_in[1];
  const float* ln_b    = (const float*)d_in[2];
  const float* conv3_w = (const float*)d_in[3];
  const float* conv3_b = (const float*)d_in[4];
  const float* dw_w    = (const float*)d_in[5];
  const float* dw_b    = (const float*)d_in[6];
  const float* c1_w    = (const float*)d_in[7];
  const float* c1_b    = (const float*)d_in[8];
  const float* c2_w    = (const float*)d_in[9];
  const float* c2_b    = (const float*)d_in[10];
  const float* basep   = (const float*)d_in[11];
  const float* up_w    = (const float*)d_in[12];
  const float* up_b    = (const float*)d_in[13];
  const float* down_w  = (const float*)d_in[14];
  const float* down_b  = (const float*)d_in[15];
  float* out = (float*)d_out;

  char* wsb = (char*)d_ws;
  size_t big = (size_t)B * HWc * 64 * sizeof(ushort);  // 67,108,864
  ushort* bufA   = (ushort*)wsb;
  ushort* bufB   = (ushort*)(wsb + big);
  ushort* wfrags = (ushort*)(wsb + 2 * big);
  ushort* wmfrag = (ushort*)(wsb + 2 * big + 3 * 36864 * 2);
  float*  stats  = (float*)(wsb + 2 * big + 3 * 36864 * 2 + 8 * 4096 * 2);  // 8*64*9

  prep_w<<<54, 256, 0, stream>>>(conv3_w, up_w, down_w, wfrags);
  zero_k<<<18, 256, 0, stream>>>(stats, B * 64 * 9);
  // 1. LN: x -> bufA (NHWC bf16)
  ln_k<<<dim3(HWc / 256, B), 256, 0, stream>>>(x, ln_g, ln_b, bufA);
  // 2. conv3 + GELU + tile-sum stats: bufA -> bufB (x1), stats[k=0]
  conv_mfma<1, 0, 1><<<dim3(16, 16, B), 256, 0, stream>>>(
      bufA, wfrags + 0 * 36864, conv3_b, nullptr, bufB, nullptr, stats);
  // 3. boundary stats from x1: stats[k=1..8]
  edge_k<<<B, 256, 0, stream>>>(bufB, stats);
  // 4. MLP + blend (pooled from stats): -> wmfrag
  mlp_k<<<B, 64, 0, stream>>>(stats, dw_w, dw_b, c1_w, c1_b, c2_w, c2_b, basep, wmfrag);
  // 5. fused up conv + mix: bufB -> bufA (xm2, NHWC bf16)
  upmix_mfma<<<dim3(16, 16, B), 256, 0, stream>>>(
      bufB, wfrags + 1 * 36864, up_b, wmfrag, bufA);
  // 6. down conv + residual: bufA -> out (NCHW fp32)
  conv_mfma<0, 1, 0><<<dim3(16, 16, B), 256, 0, stream>>>(
      bufA, wfrags + 2 * 36864, down_b, x, nullptr, out, stats);
}